// Round 12
// baseline (201.135 us; speedup 1.0000x reference)
//
#include <hip/hip_runtime.h>
#include <hip/hip_bf16.h>

// Problem constants
#define M_DIM   16384     // BATCH
#define K_DIM   512       // N_FEATURES
#define NNODES  4095
#define NPERM   4096      // permuted bottom-subtree columns (128 subtrees x 32)
#define NTOP    128       // top nodes 0..126 + 1 pad
#define NWROWS  (NPERM + NTOP)
#define NBOT_BLOCKS (32 * 128)      // m fastest: B-panel shared per 128-block group
#define NTOT_BLOCKS (NBOT_BLOCKS + 128)

typedef __bf16   bf16x8 __attribute__((ext_vector_type(8)));
typedef float    floatx4 __attribute__((ext_vector_type(4)));

// 4-inst sigmoid (rel err ~1e-7; absmax 3.9e-3 vs 1.06e-2 threshold)
__device__ __forceinline__ float sigmoidf_(float z) {
    return __builtin_amdgcn_rcpf(1.f + __expf(-z));
}

__device__ __forceinline__ void gld_lds16(const void* g, void* l) {
    __builtin_amdgcn_global_load_lds(
        (const __attribute__((address_space(1))) void*)g,
        (__attribute__((address_space(3))) void*)l, 16, 0, 0);
}

// ---------------- fused conversion: X->bf16, W->permuted bf16 ----------------
__global__ __launch_bounds__(256) void cvt_all(const float* __restrict__ X,
                                               const float* __restrict__ W,
                                               const float* __restrict__ bias,
                                               const float* __restrict__ scale,
                                               __hip_bfloat16* __restrict__ Xb,
                                               __hip_bfloat16* __restrict__ Wb,
                                               float* __restrict__ bp,
                                               float* __restrict__ sp) {
    const int bid = blockIdx.x;
    if (bid < 4096) {
        const int idx = (bid * 256 + threadIdx.x) * 8;
        float4 f0 = *reinterpret_cast<const float4*>(X + idx);
        float4 f1 = *reinterpret_cast<const float4*>(X + idx + 4);
        __hip_bfloat16 h[8];
        h[0] = __float2bfloat16(f0.x); h[1] = __float2bfloat16(f0.y);
        h[2] = __float2bfloat16(f0.z); h[3] = __float2bfloat16(f0.w);
        h[4] = __float2bfloat16(f1.x); h[5] = __float2bfloat16(f1.y);
        h[6] = __float2bfloat16(f1.z); h[7] = __float2bfloat16(f1.w);
        *reinterpret_cast<int4*>(Xb + idx) = *reinterpret_cast<int4*>(h);
        return;
    }
    const int idx = ((bid - 4096) * 256 + threadIdx.x) * 8;
    const int r = idx >> 9;
    const int k = idx & 511;
    // rows 0..4095: subtree t=r>>5, slot o=r&31:
    //   o<16: d11 q=o; <24: d10; <28: d9; <30: d8; 30: d7 root; 31: pad
    //   node = 2^d-1 + (t << (d-7)) + q.   rows 4096..4223: top node c (c<127)
    int node;
    if (r < NPERM) {
        const int t = r >> 5, o = r & 31;
        int d, q;
        if (o < 16)       { d = 11; q = o; }
        else if (o < 24)  { d = 10; q = o - 16; }
        else if (o < 28)  { d = 9;  q = o - 24; }
        else if (o < 30)  { d = 8;  q = o - 28; }
        else if (o == 30) { d = 7;  q = 0; }
        else              { d = -1; q = 0; }
        node = (d < 0) ? -1 : ((1 << d) - 1 + (t << (d - 7)) + q);
    } else {
        const int c = r - NPERM;
        node = (c < 127) ? c : -1;
    }
    __hip_bfloat16 h[8];
    if (node >= 0) {
        const float* src = W + (size_t)node * 512 + k;
        float4 f0 = *reinterpret_cast<const float4*>(src);
        float4 f1 = *reinterpret_cast<const float4*>(src + 4);
        h[0] = __float2bfloat16(f0.x); h[1] = __float2bfloat16(f0.y);
        h[2] = __float2bfloat16(f0.z); h[3] = __float2bfloat16(f0.w);
        h[4] = __float2bfloat16(f1.x); h[5] = __float2bfloat16(f1.y);
        h[6] = __float2bfloat16(f1.z); h[7] = __float2bfloat16(f1.w);
    } else {
        #pragma unroll
        for (int i = 0; i < 8; ++i) h[i] = __float2bfloat16(0.f);
    }
    *reinterpret_cast<int4*>(Wb + idx) = *reinterpret_cast<int4*>(h);
    if (k == 0) {
        bp[r] = (node >= 0) ? bias[node]  : 0.f;
        sp[r] = (node >= 0) ? scale[node] : 1.f;
    }
}

// ---------------- GEMM + sigmoid + bottom-5-level fold ----------------
// flat grid, M FASTEST (R12): 128 consecutive blocks share one 128 KB B-panel
// -> B stays L2-resident per XCD (round-robin dispatch); A (16 MB) cycles via
// L3. bid>=4096: top-node tiles. DOUBLE-BUFFERED rolled K-loop (R8-proven),
// XOR-swizzled staging/reads (R5-proven). ROLLED loop (R6: full unroll races).
#define PT_STRIDE 135   // halves; odd stride breaks pow2 bank aliasing in fold
#define BUFB 32768      // bytes per (A+B) buffer
__global__ __launch_bounds__(256) void gemm_fold(
    const __hip_bfloat16* __restrict__ A,   // [16384][512]
    const __hip_bfloat16* __restrict__ B,   // [4224][512] permuted
    const float* __restrict__ bp,           // [4224]
    const float* __restrict__ sp,           // [4224]
    const float* __restrict__ leaves,       // [4096]
    float* __restrict__ partial,            // [16384][128]
    _Float16* __restrict__ ptop)            // [16384][128]
{
    __shared__ char smem[66560] __attribute__((aligned(16)));
    // buf0: A @0, B @16384 ; buf1: A @32768, B @49152
    _Float16* pt  = (_Float16*)smem;                      // epilogue overlay
    float*    slf = (float*)(smem + 66048);               // 128 floats

    const int tid  = threadIdx.x;
    const int lane = tid & 63;
    const int wv   = tid >> 6;
    const int bid  = blockIdx.x;
    int tile_m, tile_n;
    if (bid < NBOT_BLOCKS) { tile_m = bid & 127; tile_n = bid >> 7; }   // m-fast
    else                   { tile_m = bid - NBOT_BLOCKS; tile_n = 32; }
    const int m0 = tile_m * 128;
    const int n0 = tile_n * 128;

    if (tile_n < 32 && tid < 128) slf[tid] = sigmoidf_(leaves[n0 + tid]);

    const int wm = (wv >> 1) * 64;
    const int wn = (wv & 1) * 64;
    const int lrow = lane >> 3;                     // 0..7 row within 8-row group
    const int swzb = ((lane & 7) ^ lrow) * 16;      // swizzled k-block byte offset
    const int quad = lane >> 4;
    const int l15  = lane & 15;
    const int xr   = l15 & 7;                       // fragment-read XOR key

    // staging: global pointers (incremented 128 B per staged iter) + LDS bases
    const char* gAp[4];
    const char* gBp[4];
    char* sA[4];
    char* sB[4];
    #pragma unroll
    for (int i = 0; i < 4; ++i) {
        const int rbase = i * 32 + wv * 8;          // wave-uniform, mult of 8
        gAp[i] = (const char*)(A + (size_t)(m0 + rbase + lrow) * K_DIM) + swzb;
        gBp[i] = (const char*)(B + (size_t)(n0 + rbase + lrow) * K_DIM) + swzb;
        sA[i] = smem + rbase * 128;
        sB[i] = smem + 16384 + rbase * 128;
    }

    floatx4 acc[4][4];
    #pragma unroll
    for (int i = 0; i < 4; ++i)
        #pragma unroll
        for (int j = 0; j < 4; ++j)
            acc[i][j] = (floatx4){0.f, 0.f, 0.f, 0.f};

    // prologue: stage k0=0 into buf0
    #pragma unroll
    for (int i = 0; i < 4; ++i) {
        gld_lds16(gAp[i], sA[i]);
        gld_lds16(gBp[i], sB[i]);
        gAp[i] += 128; gBp[i] += 128;
    }

    #pragma unroll 1
    for (int k0 = 0; k0 < 8; ++k0) {
        __syncthreads();     // publishes buf(k0) (vmcnt0 drain) + role swap
        if (k0 < 7) {
            const int boff = ((k0 + 1) & 1) * BUFB;
            #pragma unroll
            for (int i = 0; i < 4; ++i) {
                gld_lds16(gAp[i], sA[i] + boff);
                gld_lds16(gBp[i], sB[i] + boff);
                gAp[i] += 128; gBp[i] += 128;
            }
        }
        const __hip_bfloat16* cA =
            (const __hip_bfloat16*)(smem + (k0 & 1) * BUFB);
        const __hip_bfloat16* cB = cA + 8192;
        #pragma unroll
        for (int kk = 0; kk < 64; kk += 32) {
            const int cb = ((kk >> 3) + quad) ^ xr;  // swizzled column block
            bf16x8 af[4], bfr[4];
            #pragma unroll
            for (int i = 0; i < 4; ++i)
                af[i] = *reinterpret_cast<const bf16x8*>(
                    &cA[(wm + i * 16 + l15) * 64 + cb * 8]);
            #pragma unroll
            for (int j = 0; j < 4; ++j)
                bfr[j] = *reinterpret_cast<const bf16x8*>(
                    &cB[(wn + j * 16 + l15) * 64 + cb * 8]);
            #pragma unroll
            for (int i = 0; i < 4; ++i)
                #pragma unroll
                for (int j = 0; j < 4; ++j)
                    acc[i][j] = __builtin_amdgcn_mfma_f32_16x16x32_bf16(
                        af[i], bfr[j], acc[i][j], 0, 0, 0);
        }
    }
    __syncthreads();         // all compute done before pt overlays buffers

    float bn[4], sn[4];
    #pragma unroll
    for (int j = 0; j < 4; ++j) {
        const int n = n0 + wn + j * 16 + l15;
        bn[j] = bp[n];
        sn[j] = sp[n];
    }

    if (tile_n == 32) {
        // top-node tile: p straight to global
        #pragma unroll
        for (int i = 0; i < 4; ++i) {
            #pragma unroll
            for (int r = 0; r < 4; ++r) {
                const int m = m0 + wm + i * 16 + quad * 4 + r;
                #pragma unroll
                for (int j = 0; j < 4; ++j) {
                    const int col = wn + j * 16 + l15;
                    ptop[(size_t)m * 128 + col] =
                        (_Float16)sigmoidf_((acc[i][j][r] + bn[j]) * sn[j]);
                }
            }
        }
        return;
    }

    // p -> LDS (fp16), then per-subtree fold of the bottom 5 levels
    #pragma unroll
    for (int i = 0; i < 4; ++i) {
        #pragma unroll
        for (int r = 0; r < 4; ++r) {
            const int row = wm + i * 16 + quad * 4 + r;
            #pragma unroll
            for (int j = 0; j < 4; ++j) {
                const int col = wn + j * 16 + l15;
                pt[row * PT_STRIDE + col] =
                    (_Float16)sigmoidf_((acc[i][j][r] + bn[j]) * sn[j]);
            }
        }
    }
    __syncthreads();

    #pragma unroll
    for (int z = 0; z < 2; ++z) {
        const int task = tid + z * 256;      // 512 = 128 rows x 4 subtrees
        const int row  = task >> 2;
        const int t    = task & 3;
        const _Float16* pp = pt + row * PT_STRIDE + t * 32;
        const float*    sl = slf + t * 32;
        float v[16];
        #pragma unroll
        for (int q = 0; q < 16; ++q) {
            const float p = (float)pp[q];
            v[q] = p * sl[2 * q] + (1.f - p) * sl[2 * q + 1];
        }
        #pragma unroll
        for (int q = 0; q < 8; ++q) {
            const float p = (float)pp[16 + q];
            v[q] = p * v[2 * q] + (1.f - p) * v[2 * q + 1];
        }
        #pragma unroll
        for (int q = 0; q < 4; ++q) {
            const float p = (float)pp[24 + q];
            v[q] = p * v[2 * q] + (1.f - p) * v[2 * q + 1];
        }
        #pragma unroll
        for (int q = 0; q < 2; ++q) {
            const float p = (float)pp[28 + q];
            v[q] = p * v[2 * q] + (1.f - p) * v[2 * q + 1];
        }
        const float p7 = (float)pp[30];
        partial[(size_t)(m0 + row) * 128 + tile_n * 4 + t] =
            p7 * v[0] + (1.f - p7) * v[1];
    }
}

// ---------------- final top-7-level fold ----------------
__global__ __launch_bounds__(256) void final_fold(
    const float* __restrict__ partial,       // [16384][128]
    const _Float16* __restrict__ ptop,       // [16384][128], node c at col c
    float* __restrict__ out)                 // [16384]
{
    __shared__ float    pL[64 * 129];        // odd dword stride
    __shared__ _Float16 pq[64 * 134];

    const int tid = threadIdx.x;
    const int m0  = blockIdx.x * 64;

    #pragma unroll
    for (int it = 0; it < 32; ++it) {
        const int idx = tid + it * 256;      // 8192 = 64*128
        const int row = idx >> 7;
        const int c   = idx & 127;
        pL[row * 129 + c] = partial[(size_t)(m0 + row) * 128 + c];
        pq[row * 134 + c] = ptop[(size_t)(m0 + row) * 128 + c];
    }
    __syncthreads();

    if (tid < 64) {
        float* v = pL + tid * 129;
        const _Float16* pr = pq + tid * 134;
        #pragma unroll
        for (int d = 6; d >= 1; --d) {
            const int base = (1 << d) - 1;
            const int cnt  = 1 << d;
            for (int q = 0; q < cnt; ++q) {
                const float p = (float)pr[base + q];
                v[q] = p * v[2 * q] + (1.f - p) * v[2 * q + 1];
            }
        }
        const float p0 = (float)pr[0];
        out[m0 + tid] = p0 * v[0] + (1.f - p0) * v[1];
    }
}

// ---------------- fp32 fallback (only if workspace too small) ----------------
__global__ __launch_bounds__(256) void tnn_fallback(
    const float* __restrict__ X, const float* __restrict__ W,
    const float* __restrict__ bias, const float* __restrict__ scale,
    const float* __restrict__ leaves, float* __restrict__ out)
{
    __shared__ float xr[512];
    __shared__ float sl[4096];
    __shared__ float pp[4096];
    __shared__ float v0[2048];
    __shared__ float v1[1024];
    const int tid  = threadIdx.x;
    const int lane = tid & 63;
    const int wv   = tid >> 6;
    const int b    = blockIdx.x;
    for (int i = tid; i < 512;  i += 256) xr[i] = X[(size_t)b * 512 + i];
    for (int i = tid; i < 4096; i += 256) sl[i] = sigmoidf_(leaves[i]);
    __syncthreads();
    for (int n = wv; n < NNODES; n += 4) {
        float sum = 0.f;
        const float* wr = W + (size_t)n * 512;
        for (int k = lane; k < 512; k += 64) sum += xr[k] * wr[k];
        #pragma unroll
        for (int off = 32; off; off >>= 1) sum += __shfl_xor(sum, off);
        if (lane == 0) pp[n] = sigmoidf_((sum + bias[n]) * scale[n]);
    }
    __syncthreads();
    for (int j = tid; j < 2048; j += 256) {
        const float p = pp[2047 + j];
        v0[j] = p * sl[2 * j] + (1.f - p) * sl[2 * j + 1];
    }
    __syncthreads();
    float* src = v0;
    float* dst = v1;
    for (int d = 10; d >= 0; --d) {
        const int width = 1 << d;
        const int start = width - 1;
        for (int j = tid; j < width; j += 256) {
            const float p = pp[start + j];
            dst[j] = p * src[2 * j] + (1.f - p) * src[2 * j + 1];
        }
        __syncthreads();
        float* t = src; src = dst; dst = t;
    }
    if (tid == 0) out[b] = src[0];
}

extern "C" void kernel_launch(void* const* d_in, const int* in_sizes, int n_in,
                              void* d_out, int out_size, void* d_ws, size_t ws_size,
                              hipStream_t stream) {
    const float* X      = (const float*)d_in[0];
    const float* W      = (const float*)d_in[1];
    const float* bias   = (const float*)d_in[2];
    const float* scale  = (const float*)d_in[3];
    const float* leaves = (const float*)d_in[4];
    float* out = (float*)d_out;

    const size_t offX  = 0;
    const size_t offW  = (size_t)M_DIM * K_DIM * 2;                 // 16 MB
    const size_t offB  = offW + (size_t)NWROWS * K_DIM * 2;         // +4.125 MB
    const size_t offS  = offB + (size_t)NWROWS * 4;
    const size_t offP  = offS + (size_t)NWROWS * 4;
    const size_t offT  = offP + (size_t)M_DIM * 128 * 4;            // +8 MB
    const size_t need  = offT + (size_t)M_DIM * 128 * 2;            // +4 MB

    if (ws_size >= need) {
        __hip_bfloat16* Xb = (__hip_bfloat16*)((char*)d_ws + offX);
        __hip_bfloat16* Wb = (__hip_bfloat16*)((char*)d_ws + offW);
        float* bp = (float*)((char*)d_ws + offB);
        float* sp = (float*)((char*)d_ws + offS);
        float* partial = (float*)((char*)d_ws + offP);
        _Float16* ptop = (_Float16*)((char*)d_ws + offT);
        cvt_all<<<4096 + 1056, 256, 0, stream>>>(X, W, bias, scale, Xb, Wb, bp, sp);
        gemm_fold<<<NTOT_BLOCKS, 256, 0, stream>>>(
            Xb, Wb, bp, sp, leaves, partial, ptop);
        final_fold<<<M_DIM / 64, 256, 0, stream>>>(partial, ptop, out);
    } else {
        tnn_fallback<<<M_DIM, 256, 0, stream>>>(X, W, bias, scale, leaves, out);
    }
}

// Round 13
// 194.534 us; speedup vs baseline: 1.0339x; 1.0339x over previous
//
#include <hip/hip_runtime.h>
#include <hip/hip_bf16.h>

// Problem constants
#define M_DIM   16384     // BATCH
#define K_DIM   512       // N_FEATURES
#define NNODES  4095
#define NPERM   4096      // permuted bottom-subtree columns (128 subtrees x 32)
#define NTOP    128       // top nodes 0..126 + 1 pad
#define NWROWS  (NPERM + NTOP)
#define NBOT_BLOCKS (32 * 128)      // n fastest: XCD/L2-aligned (session optimum)
#define NTOT_BLOCKS (NBOT_BLOCKS + 128)

typedef __bf16   bf16x8 __attribute__((ext_vector_type(8)));
typedef float    floatx4 __attribute__((ext_vector_type(4)));

// 4-inst sigmoid (rel err ~1e-7; absmax 3.9e-3 vs 1.06e-2 threshold)
__device__ __forceinline__ float sigmoidf_(float z) {
    return __builtin_amdgcn_rcpf(1.f + __expf(-z));
}

__device__ __forceinline__ void gld_lds16(const void* g, void* l) {
    __builtin_amdgcn_global_load_lds(
        (const __attribute__((address_space(1))) void*)g,
        (__attribute__((address_space(3))) void*)l, 16, 0, 0);
}

// ---------------- fused conversion: X->bf16, W->permuted bf16 ----------------
__global__ __launch_bounds__(256) void cvt_all(const float* __restrict__ X,
                                               const float* __restrict__ W,
                                               const float* __restrict__ bias,
                                               const float* __restrict__ scale,
                                               __hip_bfloat16* __restrict__ Xb,
                                               __hip_bfloat16* __restrict__ Wb,
                                               float* __restrict__ bp,
                                               float* __restrict__ sp) {
    const int bid = blockIdx.x;
    if (bid < 4096) {
        const int idx = (bid * 256 + threadIdx.x) * 8;
        float4 f0 = *reinterpret_cast<const float4*>(X + idx);
        float4 f1 = *reinterpret_cast<const float4*>(X + idx + 4);
        __hip_bfloat16 h[8];
        h[0] = __float2bfloat16(f0.x); h[1] = __float2bfloat16(f0.y);
        h[2] = __float2bfloat16(f0.z); h[3] = __float2bfloat16(f0.w);
        h[4] = __float2bfloat16(f1.x); h[5] = __float2bfloat16(f1.y);
        h[6] = __float2bfloat16(f1.z); h[7] = __float2bfloat16(f1.w);
        *reinterpret_cast<int4*>(Xb + idx) = *reinterpret_cast<int4*>(h);
        return;
    }
    const int idx = ((bid - 4096) * 256 + threadIdx.x) * 8;
    const int r = idx >> 9;
    const int k = idx & 511;
    // rows 0..4095: subtree t=r>>5, slot o=r&31:
    //   o<16: d11 q=o; <24: d10; <28: d9; <30: d8; 30: d7 root; 31: pad
    //   node = 2^d-1 + (t << (d-7)) + q.   rows 4096..4223: top node c (c<127)
    int node;
    if (r < NPERM) {
        const int t = r >> 5, o = r & 31;
        int d, q;
        if (o < 16)       { d = 11; q = o; }
        else if (o < 24)  { d = 10; q = o - 16; }
        else if (o < 28)  { d = 9;  q = o - 24; }
        else if (o < 30)  { d = 8;  q = o - 28; }
        else if (o == 30) { d = 7;  q = 0; }
        else              { d = -1; q = 0; }
        node = (d < 0) ? -1 : ((1 << d) - 1 + (t << (d - 7)) + q);
    } else {
        const int c = r - NPERM;
        node = (c < 127) ? c : -1;
    }
    __hip_bfloat16 h[8];
    if (node >= 0) {
        const float* src = W + (size_t)node * 512 + k;
        float4 f0 = *reinterpret_cast<const float4*>(src);
        float4 f1 = *reinterpret_cast<const float4*>(src + 4);
        h[0] = __float2bfloat16(f0.x); h[1] = __float2bfloat16(f0.y);
        h[2] = __float2bfloat16(f0.z); h[3] = __float2bfloat16(f0.w);
        h[4] = __float2bfloat16(f1.x); h[5] = __float2bfloat16(f1.y);
        h[6] = __float2bfloat16(f1.z); h[7] = __float2bfloat16(f1.w);
    } else {
        #pragma unroll
        for (int i = 0; i < 8; ++i) h[i] = __float2bfloat16(0.f);
    }
    *reinterpret_cast<int4*>(Wb + idx) = *reinterpret_cast<int4*>(h);
    if (k == 0) {
        bp[r] = (node >= 0) ? bias[node]  : 0.f;
        sp[r] = (node >= 0) ? scale[node] : 1.f;
    }
}

// ---------------- GEMM + sigmoid + bottom-5-level fold ----------------
// flat grid, n fastest (session optimum: R12 m-fast regressed FETCH 76->89 MB).
// DOUBLE-BUFFERED rolled K-loop, one barrier/iter (R8): stage k+1 into buf^1
// before compute on buf k -> vmcnt(0) drain at next barrier lands after a full
// compute phase. XOR-swizzled staging/reads (R5). ROLLED loop (R6: unroll races).
// Explored and rejected: BK=32/4-blocks-CU (R9, conflicts+barriers), 256x256/
// 1-block-CU (R10, phase-lock), fp8 staging (32x input quant -> fails absmax).
#define PT_STRIDE 135   // halves; odd stride breaks pow2 bank aliasing in fold
#define BUFB 32768      // bytes per (A+B) buffer
__global__ __launch_bounds__(256) void gemm_fold(
    const __hip_bfloat16* __restrict__ A,   // [16384][512]
    const __hip_bfloat16* __restrict__ B,   // [4224][512] permuted
    const float* __restrict__ bp,           // [4224]
    const float* __restrict__ sp,           // [4224]
    const float* __restrict__ leaves,       // [4096]
    float* __restrict__ partial,            // [16384][128]
    _Float16* __restrict__ ptop)            // [16384][128]
{
    __shared__ char smem[66560] __attribute__((aligned(16)));
    // buf0: A @0, B @16384 ; buf1: A @32768, B @49152
    _Float16* pt  = (_Float16*)smem;                      // epilogue overlay
    float*    slf = (float*)(smem + 66048);               // 128 floats

    const int tid  = threadIdx.x;
    const int lane = tid & 63;
    const int wv   = tid >> 6;
    const int bid  = blockIdx.x;
    int tile_m, tile_n;
    if (bid < NBOT_BLOCKS) { tile_m = bid >> 5; tile_n = bid & 31; }
    else                   { tile_m = bid - NBOT_BLOCKS; tile_n = 32; }
    const int m0 = tile_m * 128;
    const int n0 = tile_n * 128;

    if (tile_n < 32 && tid < 128) slf[tid] = sigmoidf_(leaves[n0 + tid]);

    const int wm = (wv >> 1) * 64;
    const int wn = (wv & 1) * 64;
    const int lrow = lane >> 3;                     // 0..7 row within 8-row group
    const int swzb = ((lane & 7) ^ lrow) * 16;      // swizzled k-block byte offset
    const int quad = lane >> 4;
    const int l15  = lane & 15;
    const int xr   = l15 & 7;                       // fragment-read XOR key

    // staging: global pointers (incremented 128 B per staged iter) + LDS bases
    const char* gAp[4];
    const char* gBp[4];
    char* sA[4];
    char* sB[4];
    #pragma unroll
    for (int i = 0; i < 4; ++i) {
        const int rbase = i * 32 + wv * 8;          // wave-uniform, mult of 8
        gAp[i] = (const char*)(A + (size_t)(m0 + rbase + lrow) * K_DIM) + swzb;
        gBp[i] = (const char*)(B + (size_t)(n0 + rbase + lrow) * K_DIM) + swzb;
        sA[i] = smem + rbase * 128;
        sB[i] = smem + 16384 + rbase * 128;
    }

    floatx4 acc[4][4];
    #pragma unroll
    for (int i = 0; i < 4; ++i)
        #pragma unroll
        for (int j = 0; j < 4; ++j)
            acc[i][j] = (floatx4){0.f, 0.f, 0.f, 0.f};

    // prologue: stage k0=0 into buf0
    #pragma unroll
    for (int i = 0; i < 4; ++i) {
        gld_lds16(gAp[i], sA[i]);
        gld_lds16(gBp[i], sB[i]);
        gAp[i] += 128; gBp[i] += 128;
    }

    #pragma unroll 1
    for (int k0 = 0; k0 < 8; ++k0) {
        __syncthreads();     // publishes buf(k0) (vmcnt0 drain) + role swap
        if (k0 < 7) {
            const int boff = ((k0 + 1) & 1) * BUFB;
            #pragma unroll
            for (int i = 0; i < 4; ++i) {
                gld_lds16(gAp[i], sA[i] + boff);
                gld_lds16(gBp[i], sB[i] + boff);
                gAp[i] += 128; gBp[i] += 128;
            }
        }
        const __hip_bfloat16* cA =
            (const __hip_bfloat16*)(smem + (k0 & 1) * BUFB);
        const __hip_bfloat16* cB = cA + 8192;
        #pragma unroll
        for (int kk = 0; kk < 64; kk += 32) {
            const int cb = ((kk >> 3) + quad) ^ xr;  // swizzled column block
            bf16x8 af[4], bfr[4];
            #pragma unroll
            for (int i = 0; i < 4; ++i)
                af[i] = *reinterpret_cast<const bf16x8*>(
                    &cA[(wm + i * 16 + l15) * 64 + cb * 8]);
            #pragma unroll
            for (int j = 0; j < 4; ++j)
                bfr[j] = *reinterpret_cast<const bf16x8*>(
                    &cB[(wn + j * 16 + l15) * 64 + cb * 8]);
            #pragma unroll
            for (int i = 0; i < 4; ++i)
                #pragma unroll
                for (int j = 0; j < 4; ++j)
                    acc[i][j] = __builtin_amdgcn_mfma_f32_16x16x32_bf16(
                        af[i], bfr[j], acc[i][j], 0, 0, 0);
        }
    }
    __syncthreads();         // all compute done before pt overlays buffers

    float bn[4], sn[4];
    #pragma unroll
    for (int j = 0; j < 4; ++j) {
        const int n = n0 + wn + j * 16 + l15;
        bn[j] = bp[n];
        sn[j] = sp[n];
    }

    if (tile_n == 32) {
        // top-node tile: p straight to global
        #pragma unroll
        for (int i = 0; i < 4; ++i) {
            #pragma unroll
            for (int r = 0; r < 4; ++r) {
                const int m = m0 + wm + i * 16 + quad * 4 + r;
                #pragma unroll
                for (int j = 0; j < 4; ++j) {
                    const int col = wn + j * 16 + l15;
                    ptop[(size_t)m * 128 + col] =
                        (_Float16)sigmoidf_((acc[i][j][r] + bn[j]) * sn[j]);
                }
            }
        }
        return;
    }

    // p -> LDS (fp16), then per-subtree fold of the bottom 5 levels
    #pragma unroll
    for (int i = 0; i < 4; ++i) {
        #pragma unroll
        for (int r = 0; r < 4; ++r) {
            const int row = wm + i * 16 + quad * 4 + r;
            #pragma unroll
            for (int j = 0; j < 4; ++j) {
                const int col = wn + j * 16 + l15;
                pt[row * PT_STRIDE + col] =
                    (_Float16)sigmoidf_((acc[i][j][r] + bn[j]) * sn[j]);
            }
        }
    }
    __syncthreads();

    #pragma unroll
    for (int z = 0; z < 2; ++z) {
        const int task = tid + z * 256;      // 512 = 128 rows x 4 subtrees
        const int row  = task >> 2;
        const int t    = task & 3;
        const _Float16* pp = pt + row * PT_STRIDE + t * 32;
        const float*    sl = slf + t * 32;
        float v[16];
        #pragma unroll
        for (int q = 0; q < 16; ++q) {
            const float p = (float)pp[q];
            v[q] = p * sl[2 * q] + (1.f - p) * sl[2 * q + 1];
        }
        #pragma unroll
        for (int q = 0; q < 8; ++q) {
            const float p = (float)pp[16 + q];
            v[q] = p * v[2 * q] + (1.f - p) * v[2 * q + 1];
        }
        #pragma unroll
        for (int q = 0; q < 4; ++q) {
            const float p = (float)pp[24 + q];
            v[q] = p * v[2 * q] + (1.f - p) * v[2 * q + 1];
        }
        #pragma unroll
        for (int q = 0; q < 2; ++q) {
            const float p = (float)pp[28 + q];
            v[q] = p * v[2 * q] + (1.f - p) * v[2 * q + 1];
        }
        const float p7 = (float)pp[30];
        partial[(size_t)(m0 + row) * 128 + tile_n * 4 + t] =
            p7 * v[0] + (1.f - p7) * v[1];
    }
}

// ---------------- final top-7-level fold ----------------
__global__ __launch_bounds__(256) void final_fold(
    const float* __restrict__ partial,       // [16384][128]
    const _Float16* __restrict__ ptop,       // [16384][128], node c at col c
    float* __restrict__ out)                 // [16384]
{
    __shared__ float    pL[64 * 129];        // odd dword stride
    __shared__ _Float16 pq[64 * 134];

    const int tid = threadIdx.x;
    const int m0  = blockIdx.x * 64;

    #pragma unroll
    for (int it = 0; it < 32; ++it) {
        const int idx = tid + it * 256;      // 8192 = 64*128
        const int row = idx >> 7;
        const int c   = idx & 127;
        pL[row * 129 + c] = partial[(size_t)(m0 + row) * 128 + c];
        pq[row * 134 + c] = ptop[(size_t)(m0 + row) * 128 + c];
    }
    __syncthreads();

    if (tid < 64) {
        float* v = pL + tid * 129;
        const _Float16* pr = pq + tid * 134;
        #pragma unroll
        for (int d = 6; d >= 1; --d) {
            const int base = (1 << d) - 1;
            const int cnt  = 1 << d;
            for (int q = 0; q < cnt; ++q) {
                const float p = (float)pr[base + q];
                v[q] = p * v[2 * q] + (1.f - p) * v[2 * q + 1];
            }
        }
        const float p0 = (float)pr[0];
        out[m0 + tid] = p0 * v[0] + (1.f - p0) * v[1];
    }
}

// ---------------- fp32 fallback (only if workspace too small) ----------------
__global__ __launch_bounds__(256) void tnn_fallback(
    const float* __restrict__ X, const float* __restrict__ W,
    const float* __restrict__ bias, const float* __restrict__ scale,
    const float* __restrict__ leaves, float* __restrict__ out)
{
    __shared__ float xr[512];
    __shared__ float sl[4096];
    __shared__ float pp[4096];
    __shared__ float v0[2048];
    __shared__ float v1[1024];
    const int tid  = threadIdx.x;
    const int lane = tid & 63;
    const int wv   = tid >> 6;
    const int b    = blockIdx.x;
    for (int i = tid; i < 512;  i += 256) xr[i] = X[(size_t)b * 512 + i];
    for (int i = tid; i < 4096; i += 256) sl[i] = sigmoidf_(leaves[i]);
    __syncthreads();
    for (int n = wv; n < NNODES; n += 4) {
        float sum = 0.f;
        const float* wr = W + (size_t)n * 512;
        for (int k = lane; k < 512; k += 64) sum += xr[k] * wr[k];
        #pragma unroll
        for (int off = 32; off; off >>= 1) sum += __shfl_xor(sum, off);
        if (lane == 0) pp[n] = sigmoidf_((sum + bias[n]) * scale[n]);
    }
    __syncthreads();
    for (int j = tid; j < 2048; j += 256) {
        const float p = pp[2047 + j];
        v0[j] = p * sl[2 * j] + (1.f - p) * sl[2 * j + 1];
    }
    __syncthreads();
    float* src = v0;
    float* dst = v1;
    for (int d = 10; d >= 0; --d) {
        const int width = 1 << d;
        const int start = width - 1;
        for (int j = tid; j < width; j += 256) {
            const float p = pp[start + j];
            dst[j] = p * src[2 * j] + (1.f - p) * src[2 * j + 1];
        }
        __syncthreads();
        float* t = src; src = dst; dst = t;
    }
    if (tid == 0) out[b] = src[0];
}

extern "C" void kernel_launch(void* const* d_in, const int* in_sizes, int n_in,
                              void* d_out, int out_size, void* d_ws, size_t ws_size,
                              hipStream_t stream) {
    const float* X      = (const float*)d_in[0];
    const float* W      = (const float*)d_in[1];
    const float* bias   = (const float*)d_in[2];
    const float* scale  = (const float*)d_in[3];
    const float* leaves = (const float*)d_in[4];
    float* out = (float*)d_out;

    const size_t offX  = 0;
    const size_t offW  = (size_t)M_DIM * K_DIM * 2;                 // 16 MB
    const size_t offB  = offW + (size_t)NWROWS * K_DIM * 2;         // +4.125 MB
    const size_t offS  = offB + (size_t)NWROWS * 4;
    const size_t offP  = offS + (size_t)NWROWS * 4;
    const size_t offT  = offP + (size_t)M_DIM * 128 * 4;            // +8 MB
    const size_t need  = offT + (size_t)M_DIM * 128 * 2;            // +4 MB

    if (ws_size >= need) {
        __hip_bfloat16* Xb = (__hip_bfloat16*)((char*)d_ws + offX);
        __hip_bfloat16* Wb = (__hip_bfloat16*)((char*)d_ws + offW);
        float* bp = (float*)((char*)d_ws + offB);
        float* sp = (float*)((char*)d_ws + offS);
        float* partial = (float*)((char*)d_ws + offP);
        _Float16* ptop = (_Float16*)((char*)d_ws + offT);
        cvt_all<<<4096 + 1056, 256, 0, stream>>>(X, W, bias, scale, Xb, Wb, bp, sp);
        gemm_fold<<<NTOT_BLOCKS, 256, 0, stream>>>(
            Xb, Wb, bp, sp, leaves, partial, ptop);
        final_fold<<<M_DIM / 64, 256, 0, stream>>>(partial, ptop, out);
    } else {
        tnn_fallback<<<M_DIM, 256, 0, stream>>>(X, W, bias, scale, leaves, out);
    }
}